// Round 15
// baseline (485.189 us; speedup 1.0000x reference)
//
#include <hip/hip_runtime.h>
#include <hip/hip_bf16.h>

#define NOER 100000
#define NCON 20000
#define NCLS 1000
#define FENT 64
#define HID 128
#define ESR 200000
#define EEP 400000
#define ECOV 400000
#define EBEL 100000
#define NEG 0.2f
#define NB_TOT 121000

// packed src-logit offsets (by relation)
#define SL0 0
#define SL1 NOER
#define SL2 (2*NOER)
#define SL3 (2*NOER + NCON)
#define SL4 (2*NOER + 2*NCON)
#define SL_TOT (2*NOER + 2*NCON + NCLS)
// packed dst offsets (dst-logit / CSR segment / tmp row space)
#define DL0 0
#define DL1 NOER
#define DL2 (NOER + NCON)
#define DL3 (NOER + NCON + NCLS)
#define DL4 (2*NOER + NCON + NCLS)
#define DL_TOT (2*NOER + 2*NCON + NCLS)   // 241000
#define EX_TOT 1500000
#define SCAN_B1 ((DL_TOT + 255) / 256)    // 942

// bucketed CSR fill
#define BSH 9
#define BWID (1 << BSH)                    // 512 dsts per bucket
#define NBUCK ((DL_TOT + BWID - 1) / BWID) // 471
#define EPB 4096
#define ABLK ((EX_TOT + EPB - 1) / EPB)    // 367

// 128-row GEMM tiles
#define NB_OER ((NOER + 127) / 128)        // 782
#define NB_CON ((NCON + 127) / 128)        // 157
#define NB_CLS ((NCLS + 127) / 128)        // 8

// fused prep kernel block ranges
#define CAST_BLKS ((NB_TOT * FENT / 4 + 255) / 256)   // 7563
#define MISC_B0 ABLK                    // cntA
#define MISC_B1 (MISC_B0 + CAST_BLKS)   // cast
#define MISC_B2 (MISC_B1 + 739)         // prep
#define MISC_B3 (MISC_B2 + 640)         // wvec

typedef unsigned short u16;
typedef unsigned int u32;
typedef short v8s __attribute__((ext_vector_type(8)));
typedef float v4f __attribute__((ext_vector_type(4)));
typedef u32 v4u __attribute__((ext_vector_type(4)));

__device__ __forceinline__ float b2f(u32 bits) { return __uint_as_float(bits << 16); }
__device__ __forceinline__ u16 f2b(float x) {
    __hip_bfloat16 h = __float2bfloat16(x);
    return *(u16*)&h;
}
__device__ __forceinline__ float wredsum(float p) {
#pragma unroll
    for (int off = 32; off; off >>= 1) p += __shfl_down(p, off);
    return p;
}

__device__ __forceinline__ void edge_decode(int e, const int* __restrict__ ep,
                                            const int* __restrict__ cov,
                                            const int* __restrict__ bel,
                                            const int* __restrict__ rcov,
                                            const int* __restrict__ rbel,
                                            int& s, int& g) {
    if (e < 500000) {
        if (e < EEP) { s = ep[e]; g = DL0 + ep[EEP + e]; }
        else { s = e - EEP; g = DL0 + s; }
    } else if (e < 900000)  { int i = e - 500000;  s = cov[i];  g = DL1 + cov[ECOV + i]; }
    else if (e < 1000000)   { int i = e - 900000;  s = bel[i];  g = DL2 + bel[EBEL + i]; }
    else if (e < 1400000)   { int i = e - 1000000; s = rcov[i]; g = DL3 + rcov[ECOV + i]; }
    else                    { int i = e - 1400000; s = rbel[i]; g = DL4 + rbel[EBEL + i]; }
}

// ---------------- fused prep: cntA + cast + weight-prep + wvec (independent work) ----------------
__global__ __launch_bounds__(256) void k_misc(const int* __restrict__ ep, const int* __restrict__ cov,
                                              const int* __restrict__ bel, const int* __restrict__ rcov,
                                              const int* __restrict__ rbel, int* __restrict__ counts,
                                              int* __restrict__ bhm,
                                              const float* __restrict__ e_oer, const float* __restrict__ e_con,
                                              const float* __restrict__ e_cls, u16* __restrict__ eb,
                                              const float* __restrict__ W_lin, const float* __restrict__ Wsrc,
                                              const float* __restrict__ b_gat,
                                              u16* __restrict__ Wlt, u16* __restrict__ Woer, u16* __restrict__ Wcon,
                                              u16* __restrict__ Wcls, float* __restrict__ boer,
                                              float* __restrict__ bcon, float* __restrict__ bcls2,
                                              const float* __restrict__ as_, const float* __restrict__ Wdst,
                                              const float* __restrict__ ad,
                                              float* __restrict__ wsv, float* __restrict__ wdv) {
    __shared__ int lh[NBUCK];
    int blk = blockIdx.x;
    if (blk < MISC_B0) {
        // ---- cntA ----
        for (int i = threadIdx.x; i < NBUCK; i += 256) lh[i] = 0;
        __syncthreads();
        int e0 = blk * EPB;
        for (int k = 0; k < EPB; k += 256) {
            int e = e0 + k + threadIdx.x;
            if (e < EX_TOT) {
                int s, g;
                edge_decode(e, ep, cov, bel, rcov, rbel, s, g);
                atomicAdd(counts + g, 1);
                atomicAdd(&lh[g >> BSH], 1);
            }
        }
        __syncthreads();
        for (int i = threadIdx.x; i < NBUCK; i += 256) bhm[i * ABLK + blk] = lh[i];
        return;
    }
    if (blk < MISC_B1) {
        // ---- cast ----
        int idx = (blk - MISC_B0) * 256 + threadIdx.x;
        int i4 = idx * 4;
        if (i4 >= NB_TOT * FENT) return;
        const float* src;
        if (i4 < 6400000) src = e_oer + i4;
        else if (i4 < 7680000) src = e_con + (i4 - 6400000);
        else src = e_cls + (i4 - 7680000);
        float4 v = *(const float4*)src;
        u16* d = eb + i4;
        d[0] = f2b(v.x); d[1] = f2b(v.y); d[2] = f2b(v.z); d[3] = f2b(v.w);
        return;
    }
    if (blk < MISC_B2) {
        // ---- prep ----
        int i = (blk - MISC_B1) * 256 + threadIdx.x;
        if (i < 24576) {
            int t = i / 8192, r = i % 8192, c = r >> 6, k = r & 63;
            Wlt[i] = f2b(W_lin[t * 8192 + k * 128 + c]);
            return;
        }
        i -= 24576;
        if (i < 65536) {
            int l = i >> 15, r = i & 32767, c = r >> 8, k2 = r & 255;
            int rel = 5 * l + (k2 < 128 ? 0 : 3), k = k2 & 127;
            Woer[i] = f2b(Wsrc[(size_t)rel * 16384 + k * 128 + c]);
            return;
        }
        i -= 65536;
        if (i < 65536) {
            int l = i >> 15, r = i & 32767, c = r >> 8, k2 = r & 255;
            int rel = 5 * l + (k2 < 128 ? 1 : 4), k = k2 & 127;
            Wcon[i] = f2b(Wsrc[(size_t)rel * 16384 + k * 128 + c]);
            return;
        }
        i -= 65536;
        if (i < 32768) {
            int l = i >> 14, r = i & 16383, c = r >> 7, k = r & 127;
            Wcls[i] = f2b(Wsrc[(size_t)(5 * l + 2) * 16384 + k * 128 + c]);
            return;
        }
        i -= 32768;
        if (i < 256) { int l = i >> 7, c = i & 127;
            boer[i] = 0.5f * (b_gat[(5 * l + 0) * 128 + c] + b_gat[(5 * l + 3) * 128 + c]); return; }
        i -= 256;
        if (i < 256) { int l = i >> 7, c = i & 127;
            bcon[i] = 0.5f * (b_gat[(5 * l + 1) * 128 + c] + b_gat[(5 * l + 4) * 128 + c]); return; }
        i -= 256;
        if (i < 256) { int l = i >> 7, c = i & 127;
            bcls2[i] = b_gat[(5 * l + 2) * 128 + c]; }
        return;
    }
    {
        // ---- wvec ----
        int bb = blk - MISC_B2;
        int a = bb >> 5;
        int r = ((bb & 31) << 2) + (threadIdx.x >> 6);
        int lane = threadIdx.x & 63;
        const float *W, *v;
        float* o;
        if (a < 10) { W = Wsrc + (size_t)a * HID * HID; v = as_ + a * HID; o = wsv + a * HID; }
        else { W = Wdst + (size_t)(a - 10) * HID * HID; v = ad + (a - 10) * HID; o = wdv + (a - 10) * HID; }
        float p = W[r * HID + lane] * v[lane] + W[r * HID + 64 + lane] * v[64 + lane];
        p = wredsum(p);
        if (lane == 0) o[r] = p;
    }
}

__device__ __forceinline__ int deg_bin(int d) { int b = d > 63 ? 63 : d; return 63 - b; }

// scan over counts + fused 64-bin degree histogram
__global__ void k_scan1(const int* __restrict__ counts, int* __restrict__ part,
                        int* __restrict__ bsum, int* __restrict__ bh) {
    __shared__ int sm[256];
    __shared__ int lh[64];
    if (threadIdx.x < 64) lh[threadIdx.x] = 0;
    __syncthreads();
    int i = blockIdx.x * 256 + threadIdx.x;
    int v = (i < DL_TOT) ? counts[i] : 0;
    if (i < DL_TOT) atomicAdd(&lh[deg_bin(v)], 1);
    sm[threadIdx.x] = v;
    __syncthreads();
#pragma unroll
    for (int off = 1; off < 256; off <<= 1) {
        int x = (threadIdx.x >= off) ? sm[threadIdx.x - off] : 0;
        __syncthreads();
        sm[threadIdx.x] += x;
        __syncthreads();
    }
    if (i < DL_TOT) part[i] = sm[threadIdx.x];
    if (threadIdx.x == 255) bsum[blockIdx.x] = sm[255];
    if (threadIdx.x < 64) bh[threadIdx.x * SCAN_B1 + blockIdx.x] = lh[threadIdx.x];
}

__global__ void k_scan2(int* __restrict__ bsum) {
    __shared__ int sm[1024];
    int t = threadIdx.x;
    sm[t] = (t < SCAN_B1) ? bsum[t] : 0;
    __syncthreads();
#pragma unroll
    for (int off = 1; off < 1024; off <<= 1) {
        int x = (t >= off) ? sm[t - off] : 0;
        __syncthreads();
        sm[t] += x;
        __syncthreads();
    }
    if (t < SCAN_B1) bsum[t] = sm[t];
}

// S = inclusive scan; cursor = exclusive scan (= segment begin)
__global__ void k_scan3(const int* __restrict__ part, const int* __restrict__ bsum,
                        const int* __restrict__ counts, int* __restrict__ S,
                        int* __restrict__ cursor) {
    int i = blockIdx.x * 256 + threadIdx.x;
    if (i >= DL_TOT) return;
    int b = blockIdx.x;
    int s = part[i] + (b > 0 ? bsum[b - 1] : 0);
    S[i] = s;
    cursor[i] = s - counts[i];
}

// per-bucket chunked scan over blocks
__global__ void k_bscanA(const int* __restrict__ bhm, const int* __restrict__ cursor,
                         int* __restrict__ starts) {
    __shared__ int sm[256];
    __shared__ int carry;
    int u = blockIdx.x, t = threadIdx.x;
    if (t == 0) carry = 0;
    __syncthreads();
    int base = cursor[u << BSH];
    for (int c0 = 0; c0 < ABLK; c0 += 256) {
        int i = c0 + t;
        int v = (i < ABLK) ? bhm[u * ABLK + i] : 0;
        sm[t] = v;
        __syncthreads();
#pragma unroll
        for (int off = 1; off < 256; off <<= 1) {
            int x = (t >= off) ? sm[t - off] : 0;
            __syncthreads();
            sm[t] += x;
            __syncthreads();
        }
        if (i < ABLK) starts[u * ABLK + i] = base + carry + sm[t] - v;
        __syncthreads();
        if (t == 255) carry += sm[255];
        __syncthreads();
    }
}

// scatter (s,g) pairs bucket-ordered; per-block LDS bucket cursors
__global__ __launch_bounds__(256) void k_bfillA(const int* __restrict__ ep, const int* __restrict__ cov,
                                                const int* __restrict__ bel, const int* __restrict__ rcov,
                                                const int* __restrict__ rbel,
                                                const int* __restrict__ starts, uint2* __restrict__ pairs) {
    __shared__ int lh[NBUCK];
    for (int i = threadIdx.x; i < NBUCK; i += 256) lh[i] = starts[i * ABLK + blockIdx.x];
    __syncthreads();
    int e0 = blockIdx.x * EPB;
    for (int k = 0; k < EPB; k += 256) {
        int e = e0 + k + threadIdx.x;
        if (e < EX_TOT) {
            int s, g;
            edge_decode(e, ep, cov, bel, rcov, rbel, s, g);
            int pos = atomicAdd(&lh[g >> BSH], 1);
            pairs[pos] = make_uint2((u32)s, (u32)g);
        }
    }
}

// flat placement: sequential NT pair reads, global cursor atomics, localized csr writes
__global__ void k_fill2(const uint2* __restrict__ pairs, int* __restrict__ cursor,
                        int* __restrict__ csr) {
    int i = blockIdx.x * blockDim.x + threadIdx.x;
    if (i >= EX_TOT) return;
    u32 px = __builtin_nontemporal_load(&pairs[i].x);
    u32 py = __builtin_nontemporal_load(&pairs[i].y);
    int pos = atomicAdd(cursor + py, 1);
    csr[pos] = (int)px;
}

__global__ void k_bscan(const int* __restrict__ bh, int* __restrict__ boff,
                        int* __restrict__ bintot) {
    __shared__ int sm[256];
    __shared__ int carry;
    int bin = blockIdx.x;
    if (threadIdx.x == 0) carry = 0;
    __syncthreads();
    for (int c0 = 0; c0 < SCAN_B1; c0 += 256) {
        int i = c0 + threadIdx.x;
        int v = (i < SCAN_B1) ? bh[bin * SCAN_B1 + i] : 0;
        sm[threadIdx.x] = v;
        __syncthreads();
#pragma unroll
        for (int off = 1; off < 256; off <<= 1) {
            int x = (threadIdx.x >= off) ? sm[threadIdx.x - off] : 0;
            __syncthreads();
            sm[threadIdx.x] += x;
            __syncthreads();
        }
        if (i < SCAN_B1) boff[bin * SCAN_B1 + i] = carry + sm[threadIdx.x] - v;
        __syncthreads();
        if (threadIdx.x == 255) carry += sm[255];
        __syncthreads();
    }
    if (threadIdx.x == 0) bintot[bin] = carry;
}

__global__ void k_hscan(const int* __restrict__ hist, int* __restrict__ bcur) {
    int t = threadIdx.x;
    int h = hist[t];
    int v = h;
#pragma unroll
    for (int off = 1; off < 64; off <<= 1) {
        int x = __shfl_up(v, off);
        if (t >= off) v += x;
    }
    bcur[t] = v - h;
}

// perm + sequential segment descriptors
__global__ void k_perm2(const int* __restrict__ counts, const int* __restrict__ binbase,
                        const int* __restrict__ boff, const int* __restrict__ S,
                        int* __restrict__ perm, int* __restrict__ segbeg,
                        int* __restrict__ segend) {
    __shared__ int lh[64];
    if (threadIdx.x < 64)
        lh[threadIdx.x] = binbase[threadIdx.x] + boff[threadIdx.x * SCAN_B1 + blockIdx.x];
    __syncthreads();
    int g = blockIdx.x * 256 + threadIdx.x;
    if (g >= DL_TOT) return;
    int c = counts[g];
    int se = S[g];
    int pos = atomicAdd(&lh[deg_bin(c)], 1);
    perm[pos] = g;
    segbeg[pos] = se - c;
    segend[pos] = se;
}

// ---------------- MFMA GEMM (128x128 tile) + fused logit dots ----------------
struct GemmJob {
    const u16* A0;
    const u16* A1;
    const u16* Wt;
    const float* bias;
    float scale;
    int n, K;
    u16* out;
    const float* dv0; const float* dv1; const float* dv2; const float* dv3;
    float* do0; float* do1; float* do2; float* do3;
};

__global__ __launch_bounds__(256) void k_mgemm(GemmJob j0, GemmJob j1, GemmJob j2,
                                               int nb0, int nb1) {
    __shared__ u16 lA[128][40];
    __shared__ u16 lB[128][40];
    __shared__ float dvs[4][HID];
    __shared__ float pdot[128][4];
    GemmJob J;
    int b = blockIdx.x;
    if (b < nb0) J = j0;
    else if (b < nb0 + nb1) { J = j1; b -= nb0; }
    else { J = j2; b -= nb0 + nb1; }
    const int row0 = b * 128;
    const int tid = threadIdx.x, lane = tid & 63, w = tid >> 6;
    const int wr = w >> 1, wc = w & 1;
    const int fr = lane & 15, kg = lane >> 4;
    const int astride = J.A1 ? 128 : J.K;
    const bool dots = (J.do0 != nullptr);
    if (dots) {
        for (int i = tid; i < 4 * HID; i += 256) {
            int v = i >> 7, c = i & 127;
            const float* dv = (v == 0) ? J.dv0 : (v == 1) ? J.dv1 : (v == 2) ? J.dv2 : J.dv3;
            dvs[v][c] = dv ? dv[c] : 0.f;
        }
        for (int i = tid; i < 128 * 4; i += 256) ((float*)pdot)[i] = 0.f;
    }
    v4f acc[4][4];
#pragma unroll
    for (int i = 0; i < 4; ++i)
#pragma unroll
        for (int c = 0; c < 4; ++c) acc[i][c] = (v4f){0.f, 0.f, 0.f, 0.f};

    for (int k0 = 0; k0 < J.K; k0 += 32) {
        const u16* Asrc; int kk;
        if (k0 < 128) { Asrc = J.A0; kk = k0; } else { Asrc = J.A1; kk = k0 - 128; }
        __syncthreads();
#pragma unroll
        for (int p = 0; p < 2; ++p) {   // stage A: 128 rows x 32 k
            int m = tid + p * 256;
            int r = m >> 2, seg = m & 3;
            int gr = row0 + r;
            uint4 u = make_uint4(0u, 0u, 0u, 0u);
            if (gr < J.n) u = *(const uint4*)(Asrc + (size_t)gr * astride + kk + seg * 8);
            *(uint4*)&lA[r][seg * 8] = u;
        }
#pragma unroll
        for (int i = 0; i < 2; ++i) {   // stage B^T: 128 cols x 32 k
            int m = tid * 2 + i, c = m >> 2, seg = m & 3;
            uint4 u = *(const uint4*)(J.Wt + (size_t)c * J.K + k0 + seg * 8);
            *(uint4*)&lB[c][seg * 8] = u;
        }
        __syncthreads();
        v8s a[4];
#pragma unroll
        for (int i = 0; i < 4; ++i) a[i] = *(const v8s*)&lA[64 * wr + 16 * i + fr][8 * kg];
#pragma unroll
        for (int c = 0; c < 4; ++c) {
            v8s bf = *(const v8s*)&lB[64 * wc + 16 * c + fr][8 * kg];
#pragma unroll
            for (int i = 0; i < 4; ++i)
                acc[i][c] = __builtin_amdgcn_mfma_f32_16x16x32_bf16(a[i], bf, acc[i][c], 0, 0, 0);
        }
    }
    // C write
#pragma unroll
    for (int i = 0; i < 4; ++i)
#pragma unroll
        for (int c = 0; c < 4; ++c) {
            int col = 64 * wc + 16 * c + fr;
            float bv = J.bias[col];
#pragma unroll
            for (int jj = 0; jj < 4; ++jj) {
                int gr = row0 + 64 * wr + 16 * i + 4 * kg + jj;
                if (gr < J.n) J.out[(size_t)gr * 128 + col] = f2b(acc[i][c][jj] * J.scale + bv);
            }
        }
    // fused logit dots
    if (dots) {
#pragma unroll
        for (int i = 0; i < 4; ++i)
#pragma unroll
            for (int jj = 0; jj < 4; ++jj) {
                int rl = 64 * wr + 16 * i + 4 * kg + jj;
                float hv[4];
#pragma unroll
                for (int c = 0; c < 4; ++c)
                    hv[c] = acc[i][c][jj] * J.scale + J.bias[64 * wc + 16 * c + fr];
#pragma unroll
                for (int v = 0; v < 4; ++v) {
                    float p = 0.f;
#pragma unroll
                    for (int c = 0; c < 4; ++c)
                        p = fmaf(hv[c], dvs[v][64 * wc + 16 * c + fr], p);
                    p += __shfl_xor(p, 1);
                    p += __shfl_xor(p, 2);
                    p += __shfl_xor(p, 4);
                    p += __shfl_xor(p, 8);
                    if (fr == 0) atomicAdd(&pdot[rl][v], p);
                }
            }
        __syncthreads();
        if (tid < 128) {
            int gr = row0 + tid;
            if (gr < J.n) {
                if (J.do0) J.do0[gr] = pdot[tid][0];
                if (J.do1) J.do1[gr] = pdot[tid][1];
                if (J.do2) J.do2[gr] = pdot[tid][2];
                if (J.do3) J.do3[gr] = pdot[tid][3];
            }
        }
    }
}

// ---------------- fused GAT aggregation: 16-lane group per dst, sorted + deep MLP ----------------
__global__ __launch_bounds__(256) void k_agg_all(const int* __restrict__ csr,
                                                 const int* __restrict__ perm,
                                                 const int* __restrict__ segbeg,
                                                 const int* __restrict__ segend,
                                                 const float* __restrict__ slp,
                                                 const float* __restrict__ dlp,
                                                 const u16* __restrict__ hb,
                                                 u16* __restrict__ tmp) {
    int gi = blockIdx.x * 16 + (threadIdx.x >> 4);
    if (gi >= DL_TOT) return;
    int g = perm[gi];
    int beg = segbeg[gi];
    int end = segend[gi];
    int lane = threadIdx.x & 63;
    int ks = lane & 15;
    int grpbase = lane & 48;
    int c4 = ks * 4;
    const u32* h;
    int sb;
    if (g < DL1)      { h = (const u32*)hb; sb = SL0; }
    else if (g < DL2) { h = (const u32*)hb; sb = SL1; }
    else if (g < DL3) { h = (const u32*)(hb + (size_t)NOER * HID); sb = SL2; }
    else if (g < DL4) { h = (const u32*)(hb + (size_t)NOER * HID); sb = SL3; }
    else              { h = (const u32*)(hb + (size_t)(NOER + NCON) * HID); sb = SL4; }
    float dlv = dlp[g];
    const u32* hc = h + c4;
    float acc[8] = {};
    float denp = 0.f;
    for (int c0 = beg; c0 < end; c0 += 16) {
        int nch = end - c0;
        if (nch > 16) nch = 16;
        int s_l = 0;
        float ex_l = 0.f;
        if (ks < nch) {
            s_l = __builtin_nontemporal_load(&csr[c0 + ks]);
            float lg = slp[sb + s_l] + dlv;
            lg = lg > 0.f ? lg : NEG * lg;
            ex_l = __expf(lg);
            denp += ex_l;
        }
        uint4 hu[16];
#pragma unroll
        for (int j = 0; j < 16; ++j) {
            if (j < nch) {
                int s = __shfl(s_l, grpbase + j);
                hu[j] = *(const uint4*)(hc + ((size_t)s << 6));
            }
        }
#pragma unroll
        for (int j = 0; j < 16; ++j) {
            if (j < nch) {
                float ex = __shfl(ex_l, grpbase + j);
#pragma unroll
                for (int q = 0; q < 4; ++q) {
                    u32 w = ((const u32*)&hu[j])[q];
                    acc[2 * q]     = fmaf(ex, __uint_as_float(w << 16), acc[2 * q]);
                    acc[2 * q + 1] = fmaf(ex, __uint_as_float(w & 0xffff0000u), acc[2 * q + 1]);
                }
            }
        }
    }
    denp += __shfl_xor(denp, 8);
    denp += __shfl_xor(denp, 4);
    denp += __shfl_xor(denp, 2);
    denp += __shfl_xor(denp, 1);
    float inv = (end > beg) ? 1.f / denp : 0.f;
    v4u r;
    r.x = (u32)f2b(acc[0] * inv) | ((u32)f2b(acc[1] * inv) << 16);
    r.y = (u32)f2b(acc[2] * inv) | ((u32)f2b(acc[3] * inv) << 16);
    r.z = (u32)f2b(acc[4] * inv) | ((u32)f2b(acc[5] * inv) << 16);
    r.w = (u32)f2b(acc[6] * inv) | ((u32)f2b(acc[7] * inv) << 16);
    __builtin_nontemporal_store(r, (v4u*)((u32*)tmp + (size_t)g * 64 + c4));
}

// ---------------- classifier (x-part only; h-part fused into layer-1 GEMM) ----------------
__global__ void k_score(const float* __restrict__ x, const float* __restrict__ s1h,
                        const float* __restrict__ s2h, const float* __restrict__ Wc,
                        float* __restrict__ s1, float* __restrict__ s2) {
    int t = blockIdx.x * blockDim.x + threadIdx.x;
    int n = t >> 6, lane = t & 63;
    if (n >= NOER) return;
    float xv = x[(size_t)n * FENT + lane];
    float p1 = xv * Wc[lane];
    float p2 = xv * Wc[192 + lane];
#pragma unroll
    for (int off = 32; off; off >>= 1) { p1 += __shfl_down(p1, off); p2 += __shfl_down(p2, off); }
    if (lane == 0) { s1[n] = p1 + s1h[n]; s2[n] = p2 + s2h[n]; }
}

__global__ void k_final(const int* __restrict__ src, const int* __restrict__ dst,
                        const float* __restrict__ s1, const float* __restrict__ s2,
                        const float* __restrict__ bcls, float* __restrict__ out) {
    int e = blockIdx.x * blockDim.x + threadIdx.x;
    if (e >= ESR) return;
    out[e] = s1[src[e]] + s2[dst[e]] + bcls[0];
}

extern "C" void kernel_launch(void* const* d_in, const int* in_sizes, int n_in,
                              void* d_out, int out_size, void* d_ws, size_t ws_size,
                              hipStream_t stream) {
    const float* x_oer   = (const float*)d_in[0];
    const float* e_oer   = (const float*)d_in[3];
    const float* e_con   = (const float*)d_in[4];
    const float* e_cls   = (const float*)d_in[5];
    const float* W_lin   = (const float*)d_in[6];
    const float* b_lin   = (const float*)d_in[7];
    const float* Wsrc    = (const float*)d_in[8];
    const float* Wdst    = (const float*)d_in[9];
    const float* att_src = (const float*)d_in[10];
    const float* att_dst = (const float*)d_in[11];
    const float* b_gat   = (const float*)d_in[12];
    const float* W_cls   = (const float*)d_in[13];
    const float* b_cls   = (const float*)d_in[14];
    const int* ei_sr   = (const int*)d_in[15];
    const int* ei_cov  = (const int*)d_in[16];
    const int* ei_bel  = (const int*)d_in[17];
    const int* ei_rcov = (const int*)d_in[18];
    const int* ei_rbel = (const int*)d_in[19];
    const int* ei_ep   = (const int*)d_in[20];

    float* ws = (float*)d_ws;
    size_t o = 0;
    u16* hb  = (u16*)(ws + o); o += (size_t)NB_TOT * HID / 2;
    u16* eb  = (u16*)(ws + o); o += (size_t)NB_TOT * FENT / 2;
    u16* tmp = (u16*)(ws + o); o += (size_t)DL_TOT * HID / 2;
    float* slp  = ws + o; o += SL_TOT;
    float* dlp  = ws + o; o += DL_TOT;
    float* wsv  = ws + o; o += 10 * HID;
    float* wdv  = ws + o; o += 10 * HID;
    u16* Wlt  = (u16*)(ws + o); o += 3 * HID * FENT / 2;
    u16* Woer = (u16*)(ws + o); o += 2 * HID * 256 / 2;
    u16* Wcon = (u16*)(ws + o); o += 2 * HID * 256 / 2;
    u16* Wcls = (u16*)(ws + o); o += 2 * HID * HID / 2;
    float* boerb = ws + o; o += 2 * HID;
    float* bconb = ws + o; o += 2 * HID;
    float* bcls2 = ws + o; o += 2 * HID;
    float* s1 = ws + o; o += NOER;
    float* s2 = ws + o; o += NOER;
    float* s1h = ws + o; o += NOER;
    float* s2h = ws + o; o += NOER;
    int* counts = (int*)(ws + o); o += DL_TOT;
    int* part   = (int*)(ws + o); o += DL_TOT;
    int* S      = (int*)(ws + o); o += DL_TOT;
    int* cursor = (int*)(ws + o); o += DL_TOT;
    int* perm   = (int*)(ws + o); o += DL_TOT;
    int* segbeg = (int*)(ws + o); o += DL_TOT;
    int* segend = (int*)(ws + o); o += DL_TOT;
    int* bsum   = (int*)(ws + o); o += 1024;
    int* bhm    = (int*)(ws + o); o += NBUCK * ABLK;
    int* starts = (int*)(ws + o); o += NBUCK * ABLK;
    int* bh     = (int*)(ws + o); o += 64 * SCAN_B1;
    int* boff   = (int*)(ws + o); o += 64 * SCAN_B1;
    int* bintot = (int*)(ws + o); o += 64;
    int* binbase= (int*)(ws + o); o += 64;
    uint2* pairs = (uint2*)(ws + o); o += (size_t)EX_TOT * 2;
    int* csr    = (int*)(ws + o); o += EX_TOT;

    u16* hb_con = hb + (size_t)NOER * HID;
    u16* hb_cls = hb + (size_t)(NOER + NCON) * HID;

    // ---- fused prep + CSR count ----
    hipMemsetAsync(counts, 0, DL_TOT * sizeof(int), stream);
    k_misc<<<MISC_B3, 256, 0, stream>>>(ei_ep, ei_cov, ei_bel, ei_rcov, ei_rbel, counts, bhm,
                                        e_oer, e_con, e_cls, eb,
                                        W_lin, Wsrc, b_gat, Wlt, Woer, Wcon, Wcls,
                                        boerb, bconb, bcls2,
                                        att_src, Wdst, att_dst, wsv, wdv);
    k_scan1<<<SCAN_B1, 256, 0, stream>>>(counts, part, bsum, bh);
    k_scan2<<<1, 1024, 0, stream>>>(bsum);
    k_scan3<<<SCAN_B1, 256, 0, stream>>>(part, bsum, counts, S, cursor);
    k_bscanA<<<NBUCK, 256, 0, stream>>>(bhm, cursor, starts);
    k_bfillA<<<ABLK, 256, 0, stream>>>(ei_ep, ei_cov, ei_bel, ei_rcov, ei_rbel, starts, pairs);
    k_fill2<<<(EX_TOT + 255) / 256, 256, 0, stream>>>(pairs, cursor, csr);   // mutates cursor
    k_bscan<<<64, 256, 0, stream>>>(bh, boff, bintot);
    k_hscan<<<1, 64, 0, stream>>>(bintot, binbase);
    k_perm2<<<SCAN_B1, 256, 0, stream>>>(counts, binbase, boff, S, perm, segbeg, segend);

    const int NBT = NB_OER + NB_CON + NB_CLS;   // 947

    // ---- input projections (+ fused lb=0 logit dots) ----
    {
        GemmJob ja = {eb, nullptr, Wlt, b_lin, 1.f, NOER, FENT, hb,
                      wsv + 0 * HID, wsv + 1 * HID, wdv + 0 * HID, wdv + 3 * HID,
                      slp + SL0, slp + SL1, dlp + DL0, dlp + DL3};
        GemmJob jb = {eb + (size_t)NOER * FENT, nullptr, Wlt + 8192, b_lin + 128, 1.f, NCON, FENT, hb_con,
                      wsv + 2 * HID, wsv + 3 * HID, wdv + 1 * HID, wdv + 4 * HID,
                      slp + SL2, slp + SL3, dlp + DL1, dlp + DL4};
        GemmJob jc = {eb + (size_t)(NOER + NCON) * FENT, nullptr, Wlt + 16384, b_lin + 256, 1.f, NCLS, FENT, hb_cls,
                      wsv + 4 * HID, wdv + 2 * HID, nullptr, nullptr,
                      slp + SL4, dlp + DL2, nullptr, nullptr};
        k_mgemm<<<NBT, 256, 0, stream>>>(ja, jb, jc, NB_OER, NB_CON);
    }

    for (int l = 0; l < 2; ++l) {
        k_agg_all<<<(DL_TOT + 15) / 16, 256, 0, stream>>>(csr, perm, segbeg, segend, slp, dlp, hb, tmp);
        bool nd = (l == 0);
        int nb = 5;
        // layer 0: fused next-layer logit dots; layer 1: fused classifier h-dots
        GemmJob ja = {tmp + (size_t)DL0 * HID, tmp + (size_t)DL3 * HID,
                      Woer + l * 32768, boerb + l * HID, 0.5f, NOER, 256, hb,
                      nd ? wsv + (nb + 0) * HID : W_cls + 64,
                      nd ? wsv + (nb + 1) * HID : W_cls + 256,
                      nd ? wdv + (nb + 0) * HID : nullptr,
                      nd ? wdv + (nb + 3) * HID : nullptr,
                      nd ? slp + SL0 : s1h, nd ? slp + SL1 : s2h,
                      nd ? dlp + DL0 : nullptr, nd ? dlp + DL3 : nullptr};
        GemmJob jb = {tmp + (size_t)DL1 * HID, tmp + (size_t)DL4 * HID,
                      Wcon + l * 32768, bconb + l * HID, 0.5f, NCON, 256, hb_con,
                      nd ? wsv + (nb + 2) * HID : nullptr, nd ? wsv + (nb + 3) * HID : nullptr,
                      nd ? wdv + (nb + 1) * HID : nullptr, nd ? wdv + (nb + 4) * HID : nullptr,
                      nd ? slp + SL2 : nullptr, nd ? slp + SL3 : nullptr,
                      nd ? dlp + DL1 : nullptr, nd ? dlp + DL4 : nullptr};
        GemmJob jc = {tmp + (size_t)DL2 * HID, nullptr,
                      Wcls + l * 16384, bcls2 + l * HID, 1.f, NCLS, 128, hb_cls,
                      nd ? wsv + (nb + 4) * HID : nullptr, nd ? wdv + (nb + 2) * HID : nullptr,
                      nullptr, nullptr,
                      nd ? slp + SL4 : nullptr, nd ? dlp + DL2 : nullptr, nullptr, nullptr};
        k_mgemm<<<NBT, 256, 0, stream>>>(ja, jb, jc, NB_OER, NB_CON);
    }

    k_score<<<(NOER * 64 + 255) / 256, 256, 0, stream>>>(x_oer, s1h, s2h, W_cls, s1, s2);
    k_final<<<(ESR + 255) / 256, 256, 0, stream>>>(ei_sr, ei_sr + ESR, s1, s2, b_cls, (float*)d_out);
}

// Round 16
// 464.089 us; speedup vs baseline: 1.0455x; 1.0455x over previous
//
#include <hip/hip_runtime.h>
#include <hip/hip_bf16.h>

#define NOER 100000
#define NCON 20000
#define NCLS 1000
#define FENT 64
#define HID 128
#define ESR 200000
#define EEP 400000
#define ECOV 400000
#define EBEL 100000
#define NEG 0.2f
#define NB_TOT 121000

// packed src-logit offsets (by relation)
#define SL0 0
#define SL1 NOER
#define SL2 (2*NOER)
#define SL3 (2*NOER + NCON)
#define SL4 (2*NOER + 2*NCON)
#define SL_TOT (2*NOER + 2*NCON + NCLS)
// packed dst offsets (dst-logit / CSR segment / tmp row space)
#define DL0 0
#define DL1 NOER
#define DL2 (NOER + NCON)
#define DL3 (NOER + NCON + NCLS)
#define DL4 (2*NOER + NCON + NCLS)
#define DL_TOT (2*NOER + 2*NCON + NCLS)   // 241000
#define EX_TOT 1500000
#define SCAN_B1 ((DL_TOT + 255) / 256)    // 942

// bucketed CSR fill
#define BSH 9
#define BWID (1 << BSH)                    // 512 dsts per bucket
#define NBUCK ((DL_TOT + BWID - 1) / BWID) // 471
#define EPB 4096
#define ABLK ((EX_TOT + EPB - 1) / EPB)    // 367

// 128-row GEMM tiles
#define NB_OER ((NOER + 127) / 128)        // 782
#define NB_CON ((NCON + 127) / 128)        // 157
#define NB_CLS ((NCLS + 127) / 128)        // 8

typedef unsigned short u16;
typedef unsigned int u32;
typedef short v8s __attribute__((ext_vector_type(8)));
typedef float v4f __attribute__((ext_vector_type(4)));
typedef u32 v4u __attribute__((ext_vector_type(4)));

__device__ __forceinline__ float b2f(u32 bits) { return __uint_as_float(bits << 16); }
__device__ __forceinline__ u16 f2b(float x) {
    __hip_bfloat16 h = __float2bfloat16(x);
    return *(u16*)&h;
}
__device__ __forceinline__ float wredsum(float p) {
#pragma unroll
    for (int off = 32; off; off >>= 1) p += __shfl_down(p, off);
    return p;
}

// ---------------- CSR build ----------------
__device__ __forceinline__ void edge_decode(int e, const int* __restrict__ ep,
                                            const int* __restrict__ cov,
                                            const int* __restrict__ bel,
                                            const int* __restrict__ rcov,
                                            const int* __restrict__ rbel,
                                            int& s, int& g) {
    if (e < 500000) {
        if (e < EEP) { s = ep[e]; g = DL0 + ep[EEP + e]; }
        else { s = e - EEP; g = DL0 + s; }
    } else if (e < 900000)  { int i = e - 500000;  s = cov[i];  g = DL1 + cov[ECOV + i]; }
    else if (e < 1000000)   { int i = e - 900000;  s = bel[i];  g = DL2 + bel[EBEL + i]; }
    else if (e < 1400000)   { int i = e - 1000000; s = rcov[i]; g = DL3 + rcov[ECOV + i]; }
    else                    { int i = e - 1400000; s = rbel[i]; g = DL4 + rbel[EBEL + i]; }
}

// fused: global per-dst count + per-(block,bucket) histogram
__global__ __launch_bounds__(256) void k_cntA(const int* __restrict__ ep, const int* __restrict__ cov,
                                              const int* __restrict__ bel, const int* __restrict__ rcov,
                                              const int* __restrict__ rbel, int* __restrict__ counts,
                                              int* __restrict__ bhm) {
    __shared__ int lh[NBUCK];
    for (int i = threadIdx.x; i < NBUCK; i += 256) lh[i] = 0;
    __syncthreads();
    int e0 = blockIdx.x * EPB;
    for (int k = 0; k < EPB; k += 256) {
        int e = e0 + k + threadIdx.x;
        if (e < EX_TOT) {
            int s, g;
            edge_decode(e, ep, cov, bel, rcov, rbel, s, g);
            atomicAdd(counts + g, 1);
            atomicAdd(&lh[g >> BSH], 1);
        }
    }
    __syncthreads();
    for (int i = threadIdx.x; i < NBUCK; i += 256) bhm[i * ABLK + blockIdx.x] = lh[i];
}

__device__ __forceinline__ int deg_bin(int d) { int b = d > 63 ? 63 : d; return 63 - b; }

// scan over counts + fused 64-bin degree histogram
__global__ void k_scan1(const int* __restrict__ counts, int* __restrict__ part,
                        int* __restrict__ bsum, int* __restrict__ bh) {
    __shared__ int sm[256];
    __shared__ int lh[64];
    if (threadIdx.x < 64) lh[threadIdx.x] = 0;
    __syncthreads();
    int i = blockIdx.x * 256 + threadIdx.x;
    int v = (i < DL_TOT) ? counts[i] : 0;
    if (i < DL_TOT) atomicAdd(&lh[deg_bin(v)], 1);
    sm[threadIdx.x] = v;
    __syncthreads();
#pragma unroll
    for (int off = 1; off < 256; off <<= 1) {
        int x = (threadIdx.x >= off) ? sm[threadIdx.x - off] : 0;
        __syncthreads();
        sm[threadIdx.x] += x;
        __syncthreads();
    }
    if (i < DL_TOT) part[i] = sm[threadIdx.x];
    if (threadIdx.x == 255) bsum[blockIdx.x] = sm[255];
    if (threadIdx.x < 64) bh[threadIdx.x * SCAN_B1 + blockIdx.x] = lh[threadIdx.x];
}

__global__ void k_scan2(int* __restrict__ bsum) {
    __shared__ int sm[1024];
    int t = threadIdx.x;
    sm[t] = (t < SCAN_B1) ? bsum[t] : 0;
    __syncthreads();
#pragma unroll
    for (int off = 1; off < 1024; off <<= 1) {
        int x = (t >= off) ? sm[t - off] : 0;
        __syncthreads();
        sm[t] += x;
        __syncthreads();
    }
    if (t < SCAN_B1) bsum[t] = sm[t];
}

// S = inclusive scan; cursor = exclusive scan (= segment begin)
__global__ void k_scan3(const int* __restrict__ part, const int* __restrict__ bsum,
                        const int* __restrict__ counts, int* __restrict__ S,
                        int* __restrict__ cursor) {
    int i = blockIdx.x * 256 + threadIdx.x;
    if (i >= DL_TOT) return;
    int b = blockIdx.x;
    int s = part[i] + (b > 0 ? bsum[b - 1] : 0);
    S[i] = s;
    cursor[i] = s - counts[i];
}

// per-bucket chunked scan over blocks
__global__ void k_bscanA(const int* __restrict__ bhm, const int* __restrict__ cursor,
                         int* __restrict__ starts) {
    __shared__ int sm[256];
    __shared__ int carry;
    int u = blockIdx.x, t = threadIdx.x;
    if (t == 0) carry = 0;
    __syncthreads();
    int base = cursor[u << BSH];
    for (int c0 = 0; c0 < ABLK; c0 += 256) {
        int i = c0 + t;
        int v = (i < ABLK) ? bhm[u * ABLK + i] : 0;
        sm[t] = v;
        __syncthreads();
#pragma unroll
        for (int off = 1; off < 256; off <<= 1) {
            int x = (t >= off) ? sm[t - off] : 0;
            __syncthreads();
            sm[t] += x;
            __syncthreads();
        }
        if (i < ABLK) starts[u * ABLK + i] = base + carry + sm[t] - v;
        __syncthreads();
        if (t == 255) carry += sm[255];
        __syncthreads();
    }
}

// scatter (s,g) pairs bucket-ordered; per-block LDS bucket cursors
__global__ __launch_bounds__(256) void k_bfillA(const int* __restrict__ ep, const int* __restrict__ cov,
                                                const int* __restrict__ bel, const int* __restrict__ rcov,
                                                const int* __restrict__ rbel,
                                                const int* __restrict__ starts, uint2* __restrict__ pairs) {
    __shared__ int lh[NBUCK];
    for (int i = threadIdx.x; i < NBUCK; i += 256) lh[i] = starts[i * ABLK + blockIdx.x];
    __syncthreads();
    int e0 = blockIdx.x * EPB;
    for (int k = 0; k < EPB; k += 256) {
        int e = e0 + k + threadIdx.x;
        if (e < EX_TOT) {
            int s, g;
            edge_decode(e, ep, cov, bel, rcov, rbel, s, g);
            int pos = atomicAdd(&lh[g >> BSH], 1);
            pairs[pos] = make_uint2((u32)s, (u32)g);
        }
    }
}

// flat placement: sequential pair reads, global cursor atomics, localized csr writes
__global__ void k_fill2(const uint2* __restrict__ pairs, int* __restrict__ cursor,
                        int* __restrict__ csr) {
    int i = blockIdx.x * blockDim.x + threadIdx.x;
    if (i >= EX_TOT) return;
    uint2 p = pairs[i];
    int pos = atomicAdd(cursor + p.y, 1);
    csr[pos] = (int)p.x;
}

__global__ void k_bscan(const int* __restrict__ bh, int* __restrict__ boff,
                        int* __restrict__ bintot) {
    __shared__ int sm[256];
    __shared__ int carry;
    int bin = blockIdx.x;
    if (threadIdx.x == 0) carry = 0;
    __syncthreads();
    for (int c0 = 0; c0 < SCAN_B1; c0 += 256) {
        int i = c0 + threadIdx.x;
        int v = (i < SCAN_B1) ? bh[bin * SCAN_B1 + i] : 0;
        sm[threadIdx.x] = v;
        __syncthreads();
#pragma unroll
        for (int off = 1; off < 256; off <<= 1) {
            int x = (threadIdx.x >= off) ? sm[threadIdx.x - off] : 0;
            __syncthreads();
            sm[threadIdx.x] += x;
            __syncthreads();
        }
        if (i < SCAN_B1) boff[bin * SCAN_B1 + i] = carry + sm[threadIdx.x] - v;
        __syncthreads();
        if (threadIdx.x == 255) carry += sm[255];
        __syncthreads();
    }
    if (threadIdx.x == 0) bintot[bin] = carry;
}

__global__ void k_hscan(const int* __restrict__ hist, int* __restrict__ bcur) {
    int t = threadIdx.x;
    int h = hist[t];
    int v = h;
#pragma unroll
    for (int off = 1; off < 64; off <<= 1) {
        int x = __shfl_up(v, off);
        if (t >= off) v += x;
    }
    bcur[t] = v - h;
}

// perm + sequential segment descriptors (segbeg = S - counts; cursor gets mutated by fill)
__global__ void k_perm2(const int* __restrict__ counts, const int* __restrict__ binbase,
                        const int* __restrict__ boff, const int* __restrict__ S,
                        int* __restrict__ perm, int* __restrict__ segbeg,
                        int* __restrict__ segend) {
    __shared__ int lh[64];
    if (threadIdx.x < 64)
        lh[threadIdx.x] = binbase[threadIdx.x] + boff[threadIdx.x * SCAN_B1 + blockIdx.x];
    __syncthreads();
    int g = blockIdx.x * 256 + threadIdx.x;
    if (g >= DL_TOT) return;
    int c = counts[g];
    int se = S[g];
    int pos = atomicAdd(&lh[deg_bin(c)], 1);
    perm[pos] = g;
    segbeg[pos] = se - c;
    segend[pos] = se;
}

// ---------------- prep: bf16 casts + transposed weight stacks ----------------
__global__ void k_cast(const float* __restrict__ e_oer, const float* __restrict__ e_con,
                       const float* __restrict__ e_cls, u16* __restrict__ eb) {
    int idx = blockIdx.x * blockDim.x + threadIdx.x;
    int i4 = idx * 4;
    if (i4 >= NB_TOT * FENT) return;
    const float* src;
    if (i4 < 6400000) src = e_oer + i4;
    else if (i4 < 7680000) src = e_con + (i4 - 6400000);
    else src = e_cls + (i4 - 7680000);
    float4 v = *(const float4*)src;
    u16* d = eb + i4;
    d[0] = f2b(v.x); d[1] = f2b(v.y); d[2] = f2b(v.z); d[3] = f2b(v.w);
}

__global__ void k_prep(const float* __restrict__ W_lin, const float* __restrict__ Wsrc,
                       const float* __restrict__ b_gat,
                       u16* __restrict__ Wlt, u16* __restrict__ Woer, u16* __restrict__ Wcon,
                       u16* __restrict__ Wcls, float* __restrict__ boer,
                       float* __restrict__ bcon, float* __restrict__ bcls2) {
    int i = blockIdx.x * 256 + threadIdx.x;
    if (i < 24576) {
        int t = i / 8192, r = i % 8192, c = r >> 6, k = r & 63;
        Wlt[i] = f2b(W_lin[t * 8192 + k * 128 + c]);
        return;
    }
    i -= 24576;
    if (i < 65536) {
        int l = i >> 15, r = i & 32767, c = r >> 8, k2 = r & 255;
        int rel = 5 * l + (k2 < 128 ? 0 : 3), k = k2 & 127;
        Woer[i] = f2b(Wsrc[(size_t)rel * 16384 + k * 128 + c]);
        return;
    }
    i -= 65536;
    if (i < 65536) {
        int l = i >> 15, r = i & 32767, c = r >> 8, k2 = r & 255;
        int rel = 5 * l + (k2 < 128 ? 1 : 4), k = k2 & 127;
        Wcon[i] = f2b(Wsrc[(size_t)rel * 16384 + k * 128 + c]);
        return;
    }
    i -= 65536;
    if (i < 32768) {
        int l = i >> 14, r = i & 16383, c = r >> 7, k = r & 127;
        Wcls[i] = f2b(Wsrc[(size_t)(5 * l + 2) * 16384 + k * 128 + c]);
        return;
    }
    i -= 32768;
    if (i < 256) { int l = i >> 7, c = i & 127;
        boer[i] = 0.5f * (b_gat[(5 * l + 0) * 128 + c] + b_gat[(5 * l + 3) * 128 + c]); return; }
    i -= 256;
    if (i < 256) { int l = i >> 7, c = i & 127;
        bcon[i] = 0.5f * (b_gat[(5 * l + 1) * 128 + c] + b_gat[(5 * l + 4) * 128 + c]); return; }
    i -= 256;
    if (i < 256) { int l = i >> 7, c = i & 127;
        bcls2[i] = b_gat[(5 * l + 2) * 128 + c]; }
}

__global__ void k_wvec(const float* __restrict__ Wsrc, const float* __restrict__ as_,
                       const float* __restrict__ Wdst, const float* __restrict__ ad,
                       float* __restrict__ wsv, float* __restrict__ wdv) {
    int a = blockIdx.x >> 5;
    int r = ((blockIdx.x & 31) << 2) + (threadIdx.x >> 6);
    int lane = threadIdx.x & 63;
    const float *W, *v;
    float* o;
    if (a < 10) { W = Wsrc + (size_t)a * HID * HID; v = as_ + a * HID; o = wsv + a * HID; }
    else { W = Wdst + (size_t)(a - 10) * HID * HID; v = ad + (a - 10) * HID; o = wdv + (a - 10) * HID; }
    float p = W[r * HID + lane] * v[lane] + W[r * HID + 64 + lane] * v[64 + lane];
    p = wredsum(p);
    if (lane == 0) o[r] = p;
}

// ---------------- MFMA GEMM (128x128 tile) + fused logit dots ----------------
struct GemmJob {
    const u16* A0;
    const u16* A1;
    const u16* Wt;
    const float* bias;
    float scale;
    int n, K;
    u16* out;
    const float* dv0; const float* dv1; const float* dv2; const float* dv3;
    float* do0; float* do1; float* do2; float* do3;
};

__global__ __launch_bounds__(256) void k_mgemm(GemmJob j0, GemmJob j1, GemmJob j2,
                                               int nb0, int nb1) {
    __shared__ u16 lA[128][40];
    __shared__ u16 lB[128][40];
    __shared__ float dvs[4][HID];
    __shared__ float pdot[128][4];
    GemmJob J;
    int b = blockIdx.x;
    if (b < nb0) J = j0;
    else if (b < nb0 + nb1) { J = j1; b -= nb0; }
    else { J = j2; b -= nb0 + nb1; }
    const int row0 = b * 128;
    const int tid = threadIdx.x, lane = tid & 63, w = tid >> 6;
    const int wr = w >> 1, wc = w & 1;
    const int fr = lane & 15, kg = lane >> 4;
    const int astride = J.A1 ? 128 : J.K;
    const bool dots = (J.do0 != nullptr);
    if (dots) {
        for (int i = tid; i < 4 * HID; i += 256) {
            int v = i >> 7, c = i & 127;
            const float* dv = (v == 0) ? J.dv0 : (v == 1) ? J.dv1 : (v == 2) ? J.dv2 : J.dv3;
            dvs[v][c] = dv ? dv[c] : 0.f;
        }
        for (int i = tid; i < 128 * 4; i += 256) ((float*)pdot)[i] = 0.f;
    }
    v4f acc[4][4];
#pragma unroll
    for (int i = 0; i < 4; ++i)
#pragma unroll
        for (int c = 0; c < 4; ++c) acc[i][c] = (v4f){0.f, 0.f, 0.f, 0.f};

    for (int k0 = 0; k0 < J.K; k0 += 32) {
        const u16* Asrc; int kk;
        if (k0 < 128) { Asrc = J.A0; kk = k0; } else { Asrc = J.A1; kk = k0 - 128; }
        __syncthreads();
#pragma unroll
        for (int p = 0; p < 2; ++p) {   // stage A: 128 rows x 32 k
            int m = tid + p * 256;
            int r = m >> 2, seg = m & 3;
            int gr = row0 + r;
            uint4 u = make_uint4(0u, 0u, 0u, 0u);
            if (gr < J.n) u = *(const uint4*)(Asrc + (size_t)gr * astride + kk + seg * 8);
            *(uint4*)&lA[r][seg * 8] = u;
        }
#pragma unroll
        for (int i = 0; i < 2; ++i) {   // stage B^T: 128 cols x 32 k
            int m = tid * 2 + i, c = m >> 2, seg = m & 3;
            uint4 u = *(const uint4*)(J.Wt + (size_t)c * J.K + k0 + seg * 8);
            *(uint4*)&lB[c][seg * 8] = u;
        }
        __syncthreads();
        v8s a[4];
#pragma unroll
        for (int i = 0; i < 4; ++i) a[i] = *(const v8s*)&lA[64 * wr + 16 * i + fr][8 * kg];
#pragma unroll
        for (int c = 0; c < 4; ++c) {
            v8s bf = *(const v8s*)&lB[64 * wc + 16 * c + fr][8 * kg];
#pragma unroll
            for (int i = 0; i < 4; ++i)
                acc[i][c] = __builtin_amdgcn_mfma_f32_16x16x32_bf16(a[i], bf, acc[i][c], 0, 0, 0);
        }
    }
    // C write
#pragma unroll
    for (int i = 0; i < 4; ++i)
#pragma unroll
        for (int c = 0; c < 4; ++c) {
            int col = 64 * wc + 16 * c + fr;
            float bv = J.bias[col];
#pragma unroll
            for (int jj = 0; jj < 4; ++jj) {
                int gr = row0 + 64 * wr + 16 * i + 4 * kg + jj;
                if (gr < J.n) J.out[(size_t)gr * 128 + col] = f2b(acc[i][c][jj] * J.scale + bv);
            }
        }
    // fused logit dots: raw h (scale*acc + bias) dotted with dvs
    if (dots) {
#pragma unroll
        for (int i = 0; i < 4; ++i)
#pragma unroll
            for (int jj = 0; jj < 4; ++jj) {
                int rl = 64 * wr + 16 * i + 4 * kg + jj;
                float hv[4];
#pragma unroll
                for (int c = 0; c < 4; ++c)
                    hv[c] = acc[i][c][jj] * J.scale + J.bias[64 * wc + 16 * c + fr];
#pragma unroll
                for (int v = 0; v < 4; ++v) {
                    float p = 0.f;
#pragma unroll
                    for (int c = 0; c < 4; ++c)
                        p = fmaf(hv[c], dvs[v][64 * wc + 16 * c + fr], p);
                    p += __shfl_xor(p, 1);
                    p += __shfl_xor(p, 2);
                    p += __shfl_xor(p, 4);
                    p += __shfl_xor(p, 8);
                    if (fr == 0) atomicAdd(&pdot[rl][v], p);
                }
            }
        __syncthreads();
        if (tid < 128) {
            int gr = row0 + tid;
            if (gr < J.n) {
                if (J.do0) J.do0[gr] = pdot[tid][0];
                if (J.do1) J.do1[gr] = pdot[tid][1];
                if (J.do2) J.do2[gr] = pdot[tid][2];
                if (J.do3) J.do3[gr] = pdot[tid][3];
            }
        }
    }
}

// ---------------- fused GAT aggregation: 16-lane group per dst, sorted + deep MLP ----------------
__global__ __launch_bounds__(256) void k_agg_all(const int* __restrict__ csr,
                                                 const int* __restrict__ perm,
                                                 const int* __restrict__ segbeg,
                                                 const int* __restrict__ segend,
                                                 const float* __restrict__ slp,
                                                 const float* __restrict__ dlp,
                                                 const u16* __restrict__ hb,
                                                 u16* __restrict__ tmp) {
    int gi = blockIdx.x * 16 + (threadIdx.x >> 4);
    if (gi >= DL_TOT) return;
    int g = perm[gi];
    int beg = segbeg[gi];
    int end = segend[gi];
    int lane = threadIdx.x & 63;
    int ks = lane & 15;
    int grpbase = lane & 48;
    int c4 = ks * 4;
    const u32* h;
    int sb;
    if (g < DL1)      { h = (const u32*)hb; sb = SL0; }
    else if (g < DL2) { h = (const u32*)hb; sb = SL1; }
    else if (g < DL3) { h = (const u32*)(hb + (size_t)NOER * HID); sb = SL2; }
    else if (g < DL4) { h = (const u32*)(hb + (size_t)NOER * HID); sb = SL3; }
    else              { h = (const u32*)(hb + (size_t)(NOER + NCON) * HID); sb = SL4; }
    float dlv = dlp[g];
    const u32* hc = h + c4;
    float acc[8] = {};
    float denp = 0.f;
    for (int c0 = beg; c0 < end; c0 += 16) {
        int nch = end - c0;
        if (nch > 16) nch = 16;
        int s_l = 0;
        float ex_l = 0.f;
        if (ks < nch) {
            s_l = csr[c0 + ks];
            float lg = slp[sb + s_l] + dlv;
            lg = lg > 0.f ? lg : NEG * lg;
            ex_l = __expf(lg);
            denp += ex_l;
        }
        uint4 hu[16];
#pragma unroll
        for (int j = 0; j < 16; ++j) {
            if (j < nch) {
                int s = __shfl(s_l, grpbase + j);
                hu[j] = *(const uint4*)(hc + ((size_t)s << 6));
            }
        }
#pragma unroll
        for (int j = 0; j < 16; ++j) {
            if (j < nch) {
                float ex = __shfl(ex_l, grpbase + j);
#pragma unroll
                for (int q = 0; q < 4; ++q) {
                    u32 w = ((const u32*)&hu[j])[q];
                    acc[2 * q]     = fmaf(ex, __uint_as_float(w << 16), acc[2 * q]);
                    acc[2 * q + 1] = fmaf(ex, __uint_as_float(w & 0xffff0000u), acc[2 * q + 1]);
                }
            }
        }
    }
    denp += __shfl_xor(denp, 8);
    denp += __shfl_xor(denp, 4);
    denp += __shfl_xor(denp, 2);
    denp += __shfl_xor(denp, 1);
    float inv = (end > beg) ? 1.f / denp : 0.f;
    v4u r;
    r.x = (u32)f2b(acc[0] * inv) | ((u32)f2b(acc[1] * inv) << 16);
    r.y = (u32)f2b(acc[2] * inv) | ((u32)f2b(acc[3] * inv) << 16);
    r.z = (u32)f2b(acc[4] * inv) | ((u32)f2b(acc[5] * inv) << 16);
    r.w = (u32)f2b(acc[6] * inv) | ((u32)f2b(acc[7] * inv) << 16);
    // non-temporal: tmp is stream-once data; keep L2 for the hot h tables
    __builtin_nontemporal_store(r, (v4u*)((u32*)tmp + (size_t)g * 64 + c4));
}

// ---------------- classifier ----------------
__global__ void k_score(const float* __restrict__ x, const u16* __restrict__ hb,
                        const float* __restrict__ Wc, float* __restrict__ s1,
                        float* __restrict__ s2) {
    int t = blockIdx.x * blockDim.x + threadIdx.x;
    int n = t >> 6, lane = t & 63;
    if (n >= NOER) return;
    float xv = x[(size_t)n * FENT + lane];
    u32 hu = ((const u32*)hb)[(size_t)n * 64 + lane];
    float h0 = b2f(hu & 0xffffu), h1 = b2f(hu >> 16);
    float2 wa = *(const float2*)(Wc + 64 + 2 * lane);
    float2 wb = *(const float2*)(Wc + 256 + 2 * lane);
    float p1 = xv * Wc[lane] + h0 * wa.x + h1 * wa.y;
    float p2 = xv * Wc[192 + lane] + h0 * wb.x + h1 * wb.y;
#pragma unroll
    for (int off = 32; off; off >>= 1) { p1 += __shfl_down(p1, off); p2 += __shfl_down(p2, off); }
    if (lane == 0) { s1[n] = p1; s2[n] = p2; }
}

__global__ void k_final(const int* __restrict__ src, const int* __restrict__ dst,
                        const float* __restrict__ s1, const float* __restrict__ s2,
                        const float* __restrict__ bcls, float* __restrict__ out) {
    int e = blockIdx.x * blockDim.x + threadIdx.x;
    if (e >= ESR) return;
    out[e] = s1[src[e]] + s2[dst[e]] + bcls[0];
}

extern "C" void kernel_launch(void* const* d_in, const int* in_sizes, int n_in,
                              void* d_out, int out_size, void* d_ws, size_t ws_size,
                              hipStream_t stream) {
    const float* x_oer   = (const float*)d_in[0];
    const float* e_oer   = (const float*)d_in[3];
    const float* e_con   = (const float*)d_in[4];
    const float* e_cls   = (const float*)d_in[5];
    const float* W_lin   = (const float*)d_in[6];
    const float* b_lin   = (const float*)d_in[7];
    const float* Wsrc    = (const float*)d_in[8];
    const float* Wdst    = (const float*)d_in[9];
    const float* att_src = (const float*)d_in[10];
    const float* att_dst = (const float*)d_in[11];
    const float* b_gat   = (const float*)d_in[12];
    const float* W_cls   = (const float*)d_in[13];
    const float* b_cls   = (const float*)d_in[14];
    const int* ei_sr   = (const int*)d_in[15];
    const int* ei_cov  = (const int*)d_in[16];
    const int* ei_bel  = (const int*)d_in[17];
    const int* ei_rcov = (const int*)d_in[18];
    const int* ei_rbel = (const int*)d_in[19];
    const int* ei_ep   = (const int*)d_in[20];

    float* ws = (float*)d_ws;
    size_t o = 0;
    u16* hb  = (u16*)(ws + o); o += (size_t)NB_TOT * HID / 2;
    u16* eb  = (u16*)(ws + o); o += (size_t)NB_TOT * FENT / 2;
    u16* tmp = (u16*)(ws + o); o += (size_t)DL_TOT * HID / 2;
    float* slp  = ws + o; o += SL_TOT;
    float* dlp  = ws + o; o += DL_TOT;
    float* wsv  = ws + o; o += 10 * HID;
    float* wdv  = ws + o; o += 10 * HID;
    u16* Wlt  = (u16*)(ws + o); o += 3 * HID * FENT / 2;
    u16* Woer = (u16*)(ws + o); o += 2 * HID * 256 / 2;
    u16* Wcon = (u16*)(ws + o); o += 2 * HID * 256 / 2;
    u16* Wcls = (u16*)(ws + o); o += 2 * HID * HID / 2;
    float* boerb = ws + o; o += 2 * HID;
    float* bconb = ws + o; o += 2 * HID;
    float* bcls2 = ws + o; o += 2 * HID;
    float* s1 = ws + o; o += NOER;
    float* s2 = ws + o; o += NOER;
    int* counts = (int*)(ws + o); o += DL_TOT;
    int* part   = (int*)(ws + o); o += DL_TOT;
    int* S      = (int*)(ws + o); o += DL_TOT;
    int* cursor = (int*)(ws + o); o += DL_TOT;
    int* perm   = (int*)(ws + o); o += DL_TOT;
    int* segbeg = (int*)(ws + o); o += DL_TOT;
    int* segend = (int*)(ws + o); o += DL_TOT;
    int* bsum   = (int*)(ws + o); o += 1024;
    int* bhm    = (int*)(ws + o); o += NBUCK * ABLK;
    int* starts = (int*)(ws + o); o += NBUCK * ABLK;
    int* bh     = (int*)(ws + o); o += 64 * SCAN_B1;
    int* boff   = (int*)(ws + o); o += 64 * SCAN_B1;
    int* bintot = (int*)(ws + o); o += 64;
    int* binbase= (int*)(ws + o); o += 64;
    uint2* pairs = (uint2*)(ws + o); o += (size_t)EX_TOT * 2;
    int* csr    = (int*)(ws + o); o += EX_TOT;

    u16* hb_con = hb + (size_t)NOER * HID;
    u16* hb_cls = hb + (size_t)(NOER + NCON) * HID;

    // ---- CSR build (bucketed pairs + flat placement) + descending degree sort ----
    hipMemsetAsync(counts, 0, DL_TOT * sizeof(int), stream);
    k_cntA<<<ABLK, 256, 0, stream>>>(ei_ep, ei_cov, ei_bel, ei_rcov, ei_rbel, counts, bhm);
    k_scan1<<<SCAN_B1, 256, 0, stream>>>(counts, part, bsum, bh);
    k_scan2<<<1, 1024, 0, stream>>>(bsum);
    k_scan3<<<SCAN_B1, 256, 0, stream>>>(part, bsum, counts, S, cursor);
    k_bscanA<<<NBUCK, 256, 0, stream>>>(bhm, cursor, starts);
    k_bfillA<<<ABLK, 256, 0, stream>>>(ei_ep, ei_cov, ei_bel, ei_rcov, ei_rbel, starts, pairs);
    k_fill2<<<(EX_TOT + 255) / 256, 256, 0, stream>>>(pairs, cursor, csr);   // mutates cursor
    k_bscan<<<64, 256, 0, stream>>>(bh, boff, bintot);
    k_hscan<<<1, 64, 0, stream>>>(bintot, binbase);
    k_perm2<<<SCAN_B1, 256, 0, stream>>>(counts, binbase, boff, S, perm, segbeg, segend);

    // ---- prep ----
    k_prep<<<739, 256, 0, stream>>>(W_lin, Wsrc, b_gat, Wlt, Woer, Wcon, Wcls, boerb, bconb, bcls2);
    k_cast<<<(NB_TOT * FENT / 4 + 255) / 256, 256, 0, stream>>>(e_oer, e_con, e_cls, eb);
    k_wvec<<<640, 256, 0, stream>>>(Wsrc, att_src, Wdst, att_dst, wsv, wdv);

    const int NBT = NB_OER + NB_CON + NB_CLS;   // 947

    // ---- input projections (+ fused lb=0 logit dots) ----
    {
        GemmJob ja = {eb, nullptr, Wlt, b_lin, 1.f, NOER, FENT, hb,
                      wsv + 0 * HID, wsv + 1 * HID, wdv + 0 * HID, wdv + 3 * HID,
                      slp + SL0, slp + SL1, dlp + DL0, dlp + DL3};
        GemmJob jb = {eb + (size_t)NOER * FENT, nullptr, Wlt + 8192, b_lin + 128, 1.f, NCON, FENT, hb_con,
                      wsv + 2 * HID, wsv + 3 * HID, wdv + 1 * HID, wdv + 4 * HID,
                      slp + SL2, slp + SL3, dlp + DL1, dlp + DL4};
        GemmJob jc = {eb + (size_t)(NOER + NCON) * FENT, nullptr, Wlt + 16384, b_lin + 256, 1.f, NCLS, FENT, hb_cls,
                      wsv + 4 * HID, wdv + 2 * HID, nullptr, nullptr,
                      slp + SL4, dlp + DL2, nullptr, nullptr};
        k_mgemm<<<NBT, 256, 0, stream>>>(ja, jb, jc, NB_OER, NB_CON);
    }

    for (int l = 0; l < 2; ++l) {
        k_agg_all<<<(DL_TOT + 15) / 16, 256, 0, stream>>>(csr, perm, segbeg, segend, slp, dlp, hb, tmp);
        int nb = (l + 1) * 5;   // logit-vector base for the NEXT layer (l=0 -> 5; l=1 -> none)
        bool nd = (l == 0);
        GemmJob ja = {tmp + (size_t)DL0 * HID, tmp + (size_t)DL3 * HID,
                      Woer + l * 32768, boerb + l * HID, 0.5f, NOER, 256, hb,
                      nd ? wsv + (nb + 0) * HID : nullptr, nd ? wsv + (nb + 1) * HID : nullptr,
                      nd ? wdv + (nb + 0) * HID : nullptr, nd ? wdv + (nb + 3) * HID : nullptr,
                      nd ? slp + SL0 : nullptr, nd ? slp + SL1 : nullptr,
                      nd ? dlp + DL0 : nullptr, nd ? dlp + DL3 : nullptr};
        GemmJob jb = {tmp + (size_t)DL1 * HID, tmp + (size_t)DL4 * HID,
                      Wcon + l * 32768, bconb + l * HID, 0.5f, NCON, 256, hb_con,
                      nd ? wsv + (nb + 2) * HID : nullptr, nd ? wsv + (nb + 3) * HID : nullptr,
                      nd ? wdv + (nb + 1) * HID : nullptr, nd ? wdv + (nb + 4) * HID : nullptr,
                      nd ? slp + SL2 : nullptr, nd ? slp + SL3 : nullptr,
                      nd ? dlp + DL1 : nullptr, nd ? dlp + DL4 : nullptr};
        GemmJob jc = {tmp + (size_t)DL2 * HID, nullptr,
                      Wcls + l * 16384, bcls2 + l * HID, 1.f, NCLS, 128, hb_cls,
                      nd ? wsv + (nb + 4) * HID : nullptr, nd ? wdv + (nb + 2) * HID : nullptr,
                      nullptr, nullptr,
                      nd ? slp + SL4 : nullptr, nd ? dlp + DL2 : nullptr, nullptr, nullptr};
        k_mgemm<<<NBT, 256, 0, stream>>>(ja, jb, jc, NB_OER, NB_CON);
    }

    k_score<<<(NOER * 64 + 255) / 256, 256, 0, stream>>>(x_oer, hb, W_cls, s1, s2);
    k_final<<<(ESR + 255) / 256, 256, 0, stream>>>(ei_sr, ei_sr + ESR, s1, s2, b_cls, (float*)d_out);
}